// Round 3
// baseline (635.153 us; speedup 1.0000x reference)
//
#include <hip/hip_runtime.h>
#include <stdint.h>

// W4A16 dequant-GEMM: out[M,N] = x[M,K] @ W[N,K]^T, fp32 out.
// R5: same 256x256 8-phase counted-vmcnt schedule as R4, but:
//  - MFMA 32x32x16_f16 (2382 TF ceiling vs 2075 for 16x16x32; half the
//    instruction count -> more issue slots for ds_reads)
//  - XCD swizzle pairs mblk {2x,2x+1} per XCD so each B-panel in L2 serves
//    2 concurrently-resident blocks (halves B L2-fill / HBM refetch)
// Prepasses (X->f16, W dequant->f16 in d_ws) unchanged. Fallback: fused kernel.

#define M_DIM 4096
#define N_DIM 11008
#define K_DIM 4096
#define NT    (K_DIM / 64)  // 64 K-tiles of BK=64
#define BM 128
#define BN 128
#define BK 32
#define LDAB 40

typedef _Float16 half8 __attribute__((ext_vector_type(8)));
typedef float floatx4 __attribute__((ext_vector_type(4)));
typedef float floatx16 __attribute__((ext_vector_type(16)));

__device__ __forceinline__ uint32_t pk16(float a, float b) {
    return __builtin_bit_cast(uint32_t, __builtin_amdgcn_cvt_pkrtz(a, b));
}

__device__ __forceinline__ uint32_t dq2f(uint32_t v, float sf, float nzs) {
    float wl = fmaf((float)(v & 15u), sf, nzs);
    float wh = fmaf((float)((v >> 4) & 15u), sf, nzs);
    return pk16(wl, wh);
}

__device__ __forceinline__ void gload16(const void* g, void* l) {
    __builtin_amdgcn_global_load_lds(
        (const __attribute__((address_space(1))) uint32_t*)g,
        (__attribute__((address_space(3))) uint32_t*)l, 16, 0, 0);
}

// ---------------- prepass 1: X f32 -> f16
__global__ __launch_bounds__(256) void cvt_x(const float* __restrict__ X,
                                             _Float16* __restrict__ X16) {
    size_t i = ((size_t)blockIdx.x * 256 + threadIdx.x) * 8;
    float4 a = *(const float4*)(X + i);
    float4 b = *(const float4*)(X + i + 4);
    uint4 o;
    o.x = pk16(a.x, a.y);
    o.y = pk16(a.z, a.w);
    o.z = pk16(b.x, b.y);
    o.w = pk16(b.z, b.w);
    *(uint4*)(X16 + i) = o;
}

// ---------------- prepass 2: dequant W -> f16 [N, K]
__global__ __launch_bounds__(256) void dq_w(const int* __restrict__ QW,
                                            const float* __restrict__ SC,
                                            const int* __restrict__ QZ,
                                            _Float16* __restrict__ W) {
    const int n = blockIdx.x;
    const int t = threadIdx.x;
    const int g = t >> 3;
    const uint32_t zw = (uint32_t)QZ[(size_t)n * 16 + (g >> 1)];
    const float zf = (float)((g & 1) ? ((zw >> 4) & 15u) : (zw & 15u));
    const float sf = SC[(size_t)n * 32 + g];
    const float nzs = -zf * sf;
    const int4* src = (const int4*)(QW + (size_t)n * (K_DIM / 2) + t * 8);
    int4 p0 = src[0];
    int4 p1 = src[1];
    uint4 o0, o1;
    o0.x = dq2f((uint32_t)p0.x, sf, nzs);
    o0.y = dq2f((uint32_t)p0.y, sf, nzs);
    o0.z = dq2f((uint32_t)p0.z, sf, nzs);
    o0.w = dq2f((uint32_t)p0.w, sf, nzs);
    o1.x = dq2f((uint32_t)p1.x, sf, nzs);
    o1.y = dq2f((uint32_t)p1.y, sf, nzs);
    o1.z = dq2f((uint32_t)p1.z, sf, nzs);
    o1.w = dq2f((uint32_t)p1.w, sf, nzs);
    uint4* dst = (uint4*)(W + (size_t)n * K_DIM + t * 16);
    dst[0] = o0;
    dst[1] = o1;
}

// ---------------- main GEMM: 256x256 tile, BK=64, 8 waves, 8-phase schedule,
// 32x32x16 MFMA. LDS [buf][mat][half][128][64] f16, 128 KiB (unchanged).
// Stage order per iter t (tiles 2t->buf0, 2t+1->buf1):
//   p0:(2t+1).A0  p1:(2t+1).A1  p2:(2t+2).B0  p3:(2t+2).B1
//   p4:(2t+2).A0  p5:(2t+2).A1  p6:(2t+3).B0  p7:(2t+3).B1
// vmcnt(4) before barriers closing p3/p7 (never 0 except last iter).
// XOR swizzle: 16B chunk c' = c ^ (row&7) on global SOURCE of global_load_lds
// (LDS dest linear, T21) and on the ds_read address (same involution).
// A-frag (32x32x16): row=lane&31, k=(lane>>5)*8 + kk*16 (8 contiguous f16).
// C/D: col=lane&31, row=(reg&3)+8*(reg>>2)+4*(lane>>5)  [m74/m101-verified].
__global__ __launch_bounds__(512, 1) void gemm256w(const _Float16* __restrict__ A,
                                                   const _Float16* __restrict__ B,
                                                   float* __restrict__ OUT) {
    __shared__ _Float16 lds[2][2][2][128][64];  // 128 KiB

    const int tid = threadIdx.x;
    const int l = tid & 63;
    const int w = tid >> 6;   // wave 0..7
    const int wm = w & 1;     // M 128-row half
    const int wn = w >> 1;    // N 64-col quarter

    // XCD swizzle with B-panel pairing: XCD x owns mblks {2x, 2x+1};
    // consecutive t alternate mblk so both resident blocks of a given nblk
    // share the B-panel in the same XCD L2.
    const int bid = blockIdx.x;            // 688 = 8 XCDs x 86
    const int xcd = bid & 7;
    const int t_  = bid >> 3;              // 0..85
    const int nblk = t_ >> 1;              // 0..42
    const int mblk = xcd * 2 + (t_ & 1);   // 0..15

    // staging source (per-thread; col chunk pre-swizzled by row&7)
    const int sr = l >> 3;                    // row within wave's 8-row slab
    const int scol = ((l & 7) ^ sr) * 8;      // swizzled f16 col
    const _Float16* aSrc = A + (size_t)(mblk * 256 + w * 8 + sr) * K_DIM + scol;
    const _Float16* bSrc = B + (size_t)(nblk * 256 + w * 8 + sr) * K_DIM + scol;

    auto STAGE = [&](int buf, int mat, int hf, int kt) {
        const _Float16* s = (mat ? bSrc : aSrc) + (size_t)(hf * 128) * K_DIM + kt * 64;
        gload16(s, &lds[buf][mat][hf][w * 8][0]);
        gload16(s + (size_t)64 * K_DIM, &lds[buf][mat][hf][64 + w * 8][0]);
    };

    const int fr  = l & 31;             // frag row (m or n) within 32
    const int hi8 = (l >> 5) * 8;       // k-offset of this lane's 8-elem chunk
    const int swz = (l & 7) << 3;       // read-side XOR (f16 units)
    floatx16 acc[4][2] = {};            // 4 m-frags x 2 n-frags of 32x32

    // prologue: t0.B, t0.A, t1.B  (12 loads) -> wait tile0 complete
    STAGE(0, 1, 0, 0); STAGE(0, 1, 1, 0);
    STAGE(0, 0, 0, 0); STAGE(0, 0, 1, 0);
    STAGE(1, 1, 0, 1); STAGE(1, 1, 1, 1);
    asm volatile("s_waitcnt vmcnt(4)" ::: "memory");
    __builtin_amdgcn_s_barrier();

    for (int t = 0; t < 32; ++t) {
        const bool notlast = (t < 31);
#pragma unroll
        for (int hi = 0; hi < 2; ++hi) {  // tile 2t+hi from buffer hi
            const _Float16* pA = &lds[hi][0][wm][0][0];
            const _Float16* pB = &lds[hi][1][wn >> 1][(wn & 1) * 64][0];
            half8 bf[2][4];
#pragma unroll
            for (int q = 0; q < 4; ++q) {   // phase: m-frag q
                const int p = hi * 4 + q;
                half8 af[4];
#pragma unroll
                for (int kk = 0; kk < 4; ++kk)
                    af[kk] = *(const half8*)(pA + (q * 32 + fr) * 64
                                             + ((kk * 16 + hi8) ^ swz));
                if (q == 0) {
#pragma unroll
                    for (int nf = 0; nf < 2; ++nf)
#pragma unroll
                        for (int kk = 0; kk < 4; ++kk)
                            bf[nf][kk] = *(const half8*)(pB + (nf * 32 + fr) * 64
                                                         + ((kk * 16 + hi8) ^ swz));
                }
                // stage one half-tile (phase table)
                {
                    const int off = (p < 2) ? 1 : (p < 6 ? 2 : 3);
                    const int mat = (p == 2 || p == 3 || p == 6 || p == 7) ? 1 : 0;
                    const int hf = p & 1;
                    const int skt = 2 * t + off;
                    if (skt < NT) STAGE(off & 1, mat, hf, skt);
                }
                if (p == 3 || p == 7) {
                    if (notlast) asm volatile("s_waitcnt vmcnt(4)" ::: "memory");
                    else         asm volatile("s_waitcnt vmcnt(0)" ::: "memory");
                }
                __builtin_amdgcn_s_barrier();
                asm volatile("s_waitcnt lgkmcnt(0)");
                __builtin_amdgcn_s_setprio(1);
#pragma unroll
                for (int kk = 0; kk < 4; ++kk)
#pragma unroll
                    for (int nf = 0; nf < 2; ++nf)
                        acc[q][nf] = __builtin_amdgcn_mfma_f32_32x32x16_f16(
                            af[kk], bf[nf][kk], acc[q][nf], 0, 0, 0);
                __builtin_amdgcn_s_setprio(0);
                __builtin_amdgcn_s_barrier();
            }
        }
    }

    // epilogue: C/D col=lane&31, row=(r&3)+8*(r>>2)+4*(lane>>5)
    const int m0 = mblk * 256 + wm * 128 + ((l >> 5) << 2);
    const int n0 = nblk * 256 + wn * 64 + fr;
#pragma unroll
    for (int mf = 0; mf < 4; ++mf)
#pragma unroll
        for (int nf = 0; nf < 2; ++nf)
#pragma unroll
            for (int r = 0; r < 16; ++r)
                OUT[(size_t)(m0 + mf * 32 + (r & 3) + 8 * (r >> 2)) * N_DIM
                    + (n0 + nf * 32)] = acc[mf][nf][r];
}

// ---------------- fallback: fused kernel (used only if ws too small)
__global__ __launch_bounds__(256) void w4a16_gemm(
    const float* __restrict__ X,
    const int* __restrict__ QW,
    const float* __restrict__ SC,
    const int* __restrict__ QZ,
    float* __restrict__ OUT)
{
    const int tid  = threadIdx.x;
    const int lane = tid & 63;
    const int wave = tid >> 6;
    const int wm = wave & 1;
    const int wn = wave >> 1;

    const int nblk = blockIdx.x;
    const int mblk = blockIdx.y;

    __shared__ alignas(16) _Float16 As[BM][LDAB];
    __shared__ alignas(16) _Float16 Bs[BN][LDAB];

    const float* gA[4];
    _Float16* lA[4];
#pragma unroll
    for (int i = 0; i < 4; ++i) {
        const int c = tid + 256 * i;
        const int row = c >> 3, sub = c & 7;
        gA[i] = X + (size_t)(mblk * BM + row) * K_DIM + sub * 4;
        lA[i] = &As[row][sub * 4];
    }

    const int r0 = tid >> 2, q0 = tid & 3;
    const int r1 = r0 + 64;
    const int* gB0 = QW + (size_t)(nblk * BN + r0) * (K_DIM / 2) + q0 * 4;
    const int* gB1 = QW + (size_t)(nblk * BN + r1) * (K_DIM / 2) + q0 * 4;
    const float* sc0 = SC + (size_t)(nblk * BN + r0) * 32;
    const float* sc1 = SC + (size_t)(nblk * BN + r1) * 32;
    const int* qz0 = QZ + (size_t)(nblk * BN + r0) * 16;
    const int* qz1 = QZ + (size_t)(nblk * BN + r1) * 16;

    floatx4 acc[4][4] = {};

    const int fr = lane & 15;
    const int k8 = (lane >> 4) * 8;

    for (int g = 0; g < 32; ++g) {
        const uint32_t zw0 = (uint32_t)qz0[g >> 1];
        const uint32_t zw1 = (uint32_t)qz1[g >> 1];
        const float zf0 = (float)((g & 1) ? ((zw0 >> 4) & 15u) : (zw0 & 15u));
        const float zf1 = (float)((g & 1) ? ((zw1 >> 4) & 15u) : (zw1 & 15u));
        const float sf0 = sc0[g];
        const float sf1 = sc1[g];
        const float nzs0 = -zf0 * sf0;
        const float nzs1 = -zf1 * sf1;

#pragma unroll
        for (int kk = 0; kk < 4; ++kk) {
            const int kt = (g << 2) | kk;

            float4 av[4];
#pragma unroll
            for (int i = 0; i < 4; ++i)
                av[i] = *(const float4*)(gA[i] + (size_t)kt * BK);
            int4 p0 = *(const int4*)(gB0 + kt * 16);
            int4 p1 = *(const int4*)(gB1 + kt * 16);

            uint2 wa[4];
#pragma unroll
            for (int i = 0; i < 4; ++i) {
                wa[i].x = pk16(av[i].x, av[i].y);
                wa[i].y = pk16(av[i].z, av[i].w);
            }
            uint4 b0, b1;
            b0.x = dq2f((uint32_t)p0.x, sf0, nzs0);
            b0.y = dq2f((uint32_t)p0.y, sf0, nzs0);
            b0.z = dq2f((uint32_t)p0.z, sf0, nzs0);
            b0.w = dq2f((uint32_t)p0.w, sf0, nzs0);
            b1.x = dq2f((uint32_t)p1.x, sf1, nzs1);
            b1.y = dq2f((uint32_t)p1.y, sf1, nzs1);
            b1.z = dq2f((uint32_t)p1.z, sf1, nzs1);
            b1.w = dq2f((uint32_t)p1.w, sf1, nzs1);

#pragma unroll
            for (int i = 0; i < 4; ++i)
                *(uint2*)lA[i] = wa[i];
            *(uint4*)&Bs[r0][q0 * 8] = b0;
            *(uint4*)&Bs[r1][q0 * 8] = b1;
            __syncthreads();

            half8 a[4], b[4];
#pragma unroll
            for (int i = 0; i < 4; ++i) {
                a[i] = *(const half8*)&As[wm * 64 + i * 16 + fr][k8];
                b[i] = *(const half8*)&Bs[wn * 64 + i * 16 + fr][k8];
            }
#pragma unroll
            for (int i = 0; i < 4; ++i)
#pragma unroll
                for (int j = 0; j < 4; ++j)
                    acc[i][j] = __builtin_amdgcn_mfma_f32_16x16x32_f16(
                        a[i], b[j], acc[i][j], 0, 0, 0);
            __syncthreads();
        }
    }

    const int m0 = mblk * BM + wm * 64 + ((lane >> 4) << 2);
    const int n0 = nblk * BN + wn * 64 + fr;
#pragma unroll
    for (int i = 0; i < 4; ++i)
#pragma unroll
        for (int j = 0; j < 4; ++j)
#pragma unroll
            for (int r = 0; r < 4; ++r)
                OUT[(size_t)(m0 + i * 16 + r) * N_DIM + (n0 + j * 16)] = acc[i][j][r];
}

extern "C" void kernel_launch(void* const* d_in, const int* in_sizes, int n_in,
                              void* d_out, int out_size, void* d_ws, size_t ws_size,
                              hipStream_t stream) {
    const float* X  = (const float*)d_in[0];
    const int*   QW = (const int*)d_in[1];
    const float* SC = (const float*)d_in[2];
    const int*   QZ = (const int*)d_in[3];
    float*       OUT = (float*)d_out;

    const size_t needW = (size_t)N_DIM * K_DIM * 2;  // 90.2 MB f16 weights
    const size_t needX = (size_t)M_DIM * K_DIM * 2;  // 33.6 MB f16 activations

    if (ws_size >= needW + needX) {
        _Float16* W16 = (_Float16*)d_ws;
        _Float16* X16 = (_Float16*)((char*)d_ws + needW);
        cvt_x<<<dim3((M_DIM * (size_t)K_DIM) / (256 * 8)), dim3(256), 0, stream>>>(X, X16);
        dq_w<<<dim3(N_DIM), dim3(256), 0, stream>>>(QW, SC, QZ, W16);
        gemm256w<<<dim3((M_DIM / 256) * (N_DIM / 256)), dim3(512), 0, stream>>>(X16, W16, OUT);
    } else {
        w4a16_gemm<<<dim3(N_DIM / BN, M_DIM / BM), dim3(256), 0, stream>>>(X, QW, SC, QZ, OUT);
    }
}

// Round 4
// 594.202 us; speedup vs baseline: 1.0689x; 1.0689x over previous
//
#include <hip/hip_runtime.h>
#include <stdint.h>

// W4A16 dequant-GEMM: out[M,N] = x[M,K] @ W[N,K]^T, fp32 out.
// R6 = R4's verified 256x256 8-phase schedule with 16x16x32 MFMA (measured
// 0 LDS bank conflicts, 355us) + R5's XCD B-panel pairing swizzle (measured
// FETCH_SIZE 742->401 MB). The R5 32x32 MFMA switch is REVERTED: it
// introduced 3.4e7 bank-conflict cycles (+4cyc per ds_read_b128) and
// regressed 355->390us despite fewer MFMA instructions.
// Prepasses (X->f16, W dequant->f16 in d_ws) unchanged. Fallback: fused kernel.

#define M_DIM 4096
#define N_DIM 11008
#define K_DIM 4096
#define NT    (K_DIM / 64)  // 64 K-tiles of BK=64
#define BM 128
#define BN 128
#define BK 32
#define LDAB 40

typedef _Float16 half8 __attribute__((ext_vector_type(8)));
typedef float floatx4 __attribute__((ext_vector_type(4)));

__device__ __forceinline__ uint32_t pk16(float a, float b) {
    return __builtin_bit_cast(uint32_t, __builtin_amdgcn_cvt_pkrtz(a, b));
}

__device__ __forceinline__ uint32_t dq2f(uint32_t v, float sf, float nzs) {
    float wl = fmaf((float)(v & 15u), sf, nzs);
    float wh = fmaf((float)((v >> 4) & 15u), sf, nzs);
    return pk16(wl, wh);
}

__device__ __forceinline__ void gload16(const void* g, void* l) {
    __builtin_amdgcn_global_load_lds(
        (const __attribute__((address_space(1))) uint32_t*)g,
        (__attribute__((address_space(3))) uint32_t*)l, 16, 0, 0);
}

// ---------------- prepass 1: X f32 -> f16
__global__ __launch_bounds__(256) void cvt_x(const float* __restrict__ X,
                                             _Float16* __restrict__ X16) {
    size_t i = ((size_t)blockIdx.x * 256 + threadIdx.x) * 8;
    float4 a = *(const float4*)(X + i);
    float4 b = *(const float4*)(X + i + 4);
    uint4 o;
    o.x = pk16(a.x, a.y);
    o.y = pk16(a.z, a.w);
    o.z = pk16(b.x, b.y);
    o.w = pk16(b.z, b.w);
    *(uint4*)(X16 + i) = o;
}

// ---------------- prepass 2: dequant W -> f16 [N, K]
__global__ __launch_bounds__(256) void dq_w(const int* __restrict__ QW,
                                            const float* __restrict__ SC,
                                            const int* __restrict__ QZ,
                                            _Float16* __restrict__ W) {
    const int n = blockIdx.x;
    const int t = threadIdx.x;
    const int g = t >> 3;
    const uint32_t zw = (uint32_t)QZ[(size_t)n * 16 + (g >> 1)];
    const float zf = (float)((g & 1) ? ((zw >> 4) & 15u) : (zw & 15u));
    const float sf = SC[(size_t)n * 32 + g];
    const float nzs = -zf * sf;
    const int4* src = (const int4*)(QW + (size_t)n * (K_DIM / 2) + t * 8);
    int4 p0 = src[0];
    int4 p1 = src[1];
    uint4 o0, o1;
    o0.x = dq2f((uint32_t)p0.x, sf, nzs);
    o0.y = dq2f((uint32_t)p0.y, sf, nzs);
    o0.z = dq2f((uint32_t)p0.z, sf, nzs);
    o0.w = dq2f((uint32_t)p0.w, sf, nzs);
    o1.x = dq2f((uint32_t)p1.x, sf, nzs);
    o1.y = dq2f((uint32_t)p1.y, sf, nzs);
    o1.z = dq2f((uint32_t)p1.z, sf, nzs);
    o1.w = dq2f((uint32_t)p1.w, sf, nzs);
    uint4* dst = (uint4*)(W + (size_t)n * K_DIM + t * 16);
    dst[0] = o0;
    dst[1] = o1;
}

// ---------------- main GEMM: 256x256 tile, BK=64, 8 waves, 8-phase schedule.
// LDS [buf][mat(A/B)][half][128][64] f16, 128 KiB. Stage order per iter t
// (computing tiles 2t->buf0, 2t+1->buf1):
//   p0:(2t+1).A0  p1:(2t+1).A1  p2:(2t+2).B0  p3:(2t+2).B1
//   p4:(2t+2).A0  p5:(2t+2).A1  p6:(2t+3).B0  p7:(2t+3).B1
// vmcnt(4) before the barrier closing p3 and p7 (never 0 except last iter);
// both waits are tight (checked against the slot dependency table).
// XOR swizzle: 16B chunk c' = c ^ (row&7), applied to global SOURCE of
// global_load_lds (LDS dest stays linear, T21) and to the ds_read address.
// XCD pairing swizzle: XCD x owns mblks {2x,2x+1}; adjacent t_ share nblk so
// each B-panel in an XCD's L2 serves 2 co-resident blocks (FETCH halved, R5).
__global__ __launch_bounds__(512, 1) void gemm256(const _Float16* __restrict__ A,
                                                  const _Float16* __restrict__ B,
                                                  float* __restrict__ OUT) {
    __shared__ _Float16 lds[2][2][2][128][64];  // 128 KiB

    const int tid = threadIdx.x;
    const int l = tid & 63;
    const int w = tid >> 6;   // wave 0..7
    const int wm = w & 1;     // M 128-row half
    const int wn = w >> 1;    // N 64-col quarter

    // T1 + pairing: 688 blocks = 8 XCDs x 86; per XCD 2 mblks x 43 nblks.
    const int bid = blockIdx.x;
    const int xcd = bid & 7;
    const int t_  = bid >> 3;              // 0..85
    const int nblk = t_ >> 1;              // 0..42
    const int mblk = xcd * 2 + (t_ & 1);   // 0..15

    // staging source (per-thread; col chunk pre-swizzled by row&7)
    const int sr = l >> 3;                    // row within wave's 8-row slab
    const int scol = ((l & 7) ^ sr) * 8;      // swizzled f16 col
    const _Float16* aSrc = A + (size_t)(mblk * 256 + w * 8 + sr) * K_DIM + scol;
    const _Float16* bSrc = B + (size_t)(nblk * 256 + w * 8 + sr) * K_DIM + scol;

    auto STAGE = [&](int buf, int mat, int hf, int kt) {
        const _Float16* s = (mat ? bSrc : aSrc) + (size_t)(hf * 128) * K_DIM + kt * 64;
        gload16(s, &lds[buf][mat][hf][w * 8][0]);
        gload16(s + (size_t)64 * K_DIM, &lds[buf][mat][hf][64 + w * 8][0]);
    };

    const int fr = l & 15;              // frag row (m or n) within 16
    const int ks = l >> 4;              // k-subgroup 0..3
    const int swz = (fr & 7) << 3;      // read-side XOR (f16 units)
    floatx4 acc[8][4] = {};

    // prologue: t0.B, t0.A, t1.B  (12 loads) -> wait tile0 complete
    STAGE(0, 1, 0, 0); STAGE(0, 1, 1, 0);
    STAGE(0, 0, 0, 0); STAGE(0, 0, 1, 0);
    STAGE(1, 1, 0, 1); STAGE(1, 1, 1, 1);
    asm volatile("s_waitcnt vmcnt(4)" ::: "memory");
    __builtin_amdgcn_s_barrier();

    for (int t = 0; t < 32; ++t) {
        const bool notlast = (t < 31);
#pragma unroll
        for (int hi = 0; hi < 2; ++hi) {  // tile 2t+hi from buffer hi
            const _Float16* pA = &lds[hi][0][wm][0][0];
            const _Float16* pB = &lds[hi][1][wn >> 1][(wn & 1) * 64][0];
            half8 bf[4][2];
#pragma unroll
            for (int q = 0; q < 4; ++q) {
                const int p = hi * 4 + q;
                // ds-reads: A frags for m-group q; B frags once per tile
                half8 af[2][2];
#pragma unroll
                for (int m2 = 0; m2 < 2; ++m2)
#pragma unroll
                    for (int kh = 0; kh < 2; ++kh)
                        af[m2][kh] = *(const half8*)(pA
                            + ((2 * q + m2) * 16 + fr) * 64
                            + ((kh * 32 + ks * 8) ^ swz));
                if (q == 0) {
#pragma unroll
                    for (int nf = 0; nf < 4; ++nf)
#pragma unroll
                        for (int kh = 0; kh < 2; ++kh)
                            bf[nf][kh] = *(const half8*)(pB
                                + (nf * 16 + fr) * 64
                                + ((kh * 32 + ks * 8) ^ swz));
                }
                // stage one half-tile (phase table)
                {
                    const int off = (p < 2) ? 1 : (p < 6 ? 2 : 3);
                    const int mat = (p == 2 || p == 3 || p == 6 || p == 7) ? 1 : 0;
                    const int hf = p & 1;
                    const int skt = 2 * t + off;
                    if (skt < NT) STAGE(off & 1, mat, hf, skt);
                }
                if (p == 3 || p == 7) {
                    if (notlast) asm volatile("s_waitcnt vmcnt(4)" ::: "memory");
                    else         asm volatile("s_waitcnt vmcnt(0)" ::: "memory");
                }
                __builtin_amdgcn_s_barrier();
                asm volatile("s_waitcnt lgkmcnt(0)");
                __builtin_amdgcn_s_setprio(1);
#pragma unroll
                for (int m2 = 0; m2 < 2; ++m2)
#pragma unroll
                    for (int nf = 0; nf < 4; ++nf)
#pragma unroll
                        for (int kh = 0; kh < 2; ++kh)
                            acc[2 * q + m2][nf] = __builtin_amdgcn_mfma_f32_16x16x32_f16(
                                af[m2][kh], bf[nf][kh], acc[2 * q + m2][nf], 0, 0, 0);
                __builtin_amdgcn_s_setprio(0);
                __builtin_amdgcn_s_barrier();
            }
        }
    }

    // epilogue: C/D layout col(n)=lane&15, row(m)=(lane>>4)*4+ri
    const int m0 = mblk * 256 + wm * 128 + ks * 4;
    const int n0 = nblk * 256 + wn * 64 + fr;
#pragma unroll
    for (int mf = 0; mf < 8; ++mf)
#pragma unroll
        for (int nf = 0; nf < 4; ++nf)
#pragma unroll
            for (int ri = 0; ri < 4; ++ri)
                OUT[(size_t)(m0 + mf * 16 + ri) * N_DIM + (n0 + nf * 16)] =
                    acc[mf][nf][ri];
}

// ---------------- fallback: fused kernel (used only if ws too small)
__global__ __launch_bounds__(256) void w4a16_gemm(
    const float* __restrict__ X,
    const int* __restrict__ QW,
    const float* __restrict__ SC,
    const int* __restrict__ QZ,
    float* __restrict__ OUT)
{
    const int tid  = threadIdx.x;
    const int lane = tid & 63;
    const int wave = tid >> 6;
    const int wm = wave & 1;
    const int wn = wave >> 1;

    const int nblk = blockIdx.x;
    const int mblk = blockIdx.y;

    __shared__ alignas(16) _Float16 As[BM][LDAB];
    __shared__ alignas(16) _Float16 Bs[BN][LDAB];

    const float* gA[4];
    _Float16* lA[4];
#pragma unroll
    for (int i = 0; i < 4; ++i) {
        const int c = tid + 256 * i;
        const int row = c >> 3, sub = c & 7;
        gA[i] = X + (size_t)(mblk * BM + row) * K_DIM + sub * 4;
        lA[i] = &As[row][sub * 4];
    }

    const int r0 = tid >> 2, q0 = tid & 3;
    const int r1 = r0 + 64;
    const int* gB0 = QW + (size_t)(nblk * BN + r0) * (K_DIM / 2) + q0 * 4;
    const int* gB1 = QW + (size_t)(nblk * BN + r1) * (K_DIM / 2) + q0 * 4;
    const float* sc0 = SC + (size_t)(nblk * BN + r0) * 32;
    const float* sc1 = SC + (size_t)(nblk * BN + r1) * 32;
    const int* qz0 = QZ + (size_t)(nblk * BN + r0) * 16;
    const int* qz1 = QZ + (size_t)(nblk * BN + r1) * 16;

    floatx4 acc[4][4] = {};

    const int fr = lane & 15;
    const int k8 = (lane >> 4) * 8;

    for (int g = 0; g < 32; ++g) {
        const uint32_t zw0 = (uint32_t)qz0[g >> 1];
        const uint32_t zw1 = (uint32_t)qz1[g >> 1];
        const float zf0 = (float)((g & 1) ? ((zw0 >> 4) & 15u) : (zw0 & 15u));
        const float zf1 = (float)((g & 1) ? ((zw1 >> 4) & 15u) : (zw1 & 15u));
        const float sf0 = sc0[g];
        const float sf1 = sc1[g];
        const float nzs0 = -zf0 * sf0;
        const float nzs1 = -zf1 * sf1;

#pragma unroll
        for (int kk = 0; kk < 4; ++kk) {
            const int kt = (g << 2) | kk;

            float4 av[4];
#pragma unroll
            for (int i = 0; i < 4; ++i)
                av[i] = *(const float4*)(gA[i] + (size_t)kt * BK);
            int4 p0 = *(const int4*)(gB0 + kt * 16);
            int4 p1 = *(const int4*)(gB1 + kt * 16);

            uint2 wa[4];
#pragma unroll
            for (int i = 0; i < 4; ++i) {
                wa[i].x = pk16(av[i].x, av[i].y);
                wa[i].y = pk16(av[i].z, av[i].w);
            }
            uint4 b0, b1;
            b0.x = dq2f((uint32_t)p0.x, sf0, nzs0);
            b0.y = dq2f((uint32_t)p0.y, sf0, nzs0);
            b0.z = dq2f((uint32_t)p0.z, sf0, nzs0);
            b0.w = dq2f((uint32_t)p0.w, sf0, nzs0);
            b1.x = dq2f((uint32_t)p1.x, sf1, nzs1);
            b1.y = dq2f((uint32_t)p1.y, sf1, nzs1);
            b1.z = dq2f((uint32_t)p1.z, sf1, nzs1);
            b1.w = dq2f((uint32_t)p1.w, sf1, nzs1);

#pragma unroll
            for (int i = 0; i < 4; ++i)
                *(uint2*)lA[i] = wa[i];
            *(uint4*)&Bs[r0][q0 * 8] = b0;
            *(uint4*)&Bs[r1][q0 * 8] = b1;
            __syncthreads();

            half8 a[4], b[4];
#pragma unroll
            for (int i = 0; i < 4; ++i) {
                a[i] = *(const half8*)&As[wm * 64 + i * 16 + fr][k8];
                b[i] = *(const half8*)&Bs[wn * 64 + i * 16 + fr][k8];
            }
#pragma unroll
            for (int i = 0; i < 4; ++i)
#pragma unroll
                for (int j = 0; j < 4; ++j)
                    acc[i][j] = __builtin_amdgcn_mfma_f32_16x16x32_f16(
                        a[i], b[j], acc[i][j], 0, 0, 0);
            __syncthreads();
        }
    }

    const int m0 = mblk * BM + wm * 64 + ((lane >> 4) << 2);
    const int n0 = nblk * BN + wn * 64 + fr;
#pragma unroll
    for (int i = 0; i < 4; ++i)
#pragma unroll
        for (int j = 0; j < 4; ++j)
#pragma unroll
            for (int r = 0; r < 4; ++r)
                OUT[(size_t)(m0 + i * 16 + r) * N_DIM + (n0 + j * 16)] = acc[i][j][r];
}

extern "C" void kernel_launch(void* const* d_in, const int* in_sizes, int n_in,
                              void* d_out, int out_size, void* d_ws, size_t ws_size,
                              hipStream_t stream) {
    const float* X  = (const float*)d_in[0];
    const int*   QW = (const int*)d_in[1];
    const float* SC = (const float*)d_in[2];
    const int*   QZ = (const int*)d_in[3];
    float*       OUT = (float*)d_out;

    const size_t needW = (size_t)N_DIM * K_DIM * 2;  // 90.2 MB f16 weights
    const size_t needX = (size_t)M_DIM * K_DIM * 2;  // 33.6 MB f16 activations

    if (ws_size >= needW + needX) {
        _Float16* W16 = (_Float16*)d_ws;
        _Float16* X16 = (_Float16*)((char*)d_ws + needW);
        cvt_x<<<dim3((M_DIM * (size_t)K_DIM) / (256 * 8)), dim3(256), 0, stream>>>(X, X16);
        dq_w<<<dim3(N_DIM), dim3(256), 0, stream>>>(QW, SC, QZ, W16);
        gemm256<<<dim3((M_DIM / 256) * (N_DIM / 256)), dim3(512), 0, stream>>>(X16, W16, OUT);
    } else {
        w4a16_gemm<<<dim3(N_DIM / BN, M_DIM / BM), dim3(256), 0, stream>>>(X, QW, SC, QZ, OUT);
    }
}